// Round 6
// baseline (497.866 us; speedup 1.0000x reference)
//
#include <hip/hip_runtime.h>
#include <math.h>

#define B 128
#define D 128
#define NMEM 100000
#define KTOT 8194
#define NEGK 8192
#define CHUNKS 16
#define CS 513  // ceil(8194/16)
#define N4 (NMEM * D / 4)                  // 3,200,000 float4 per mem array
#define NTHREADS_TOTAL (CHUNKS * B * 256)  // 524,288

// plain vector type for nontemporal builtins (HIP_vector_type is rejected)
typedef float nt4 __attribute__((ext_vector_type(4)));

// gather_copy v2: round-1 gather structure (8 lanes/k, 8 k's/wave-iter,
// register double-buffer, VGPR=64 under (256,4)) + mem->out copy fused into
// the k-loop. Cache policy fixed vs round 3: CACHED loads (mem arrays are
// LLC-resident, kept hot by the gather itself) + NON-TEMPORAL stores only
// (write-once stream, skip allocate). Copy step sits after the row-fetch
// issue so its store's vmcnt wait drains only the 2 copy loads (FIFO).
__global__ __launch_bounds__(256, 4) void gather_copy(
        const float* __restrict__ emb0, const float* __restrict__ emb1,
        const float* __restrict__ mem0, const float* __restrict__ mem1,
        const int* __restrict__ pos_idx, const int* __restrict__ neg_idx,
        float* __restrict__ partials,
        float* __restrict__ out_m0, float* __restrict__ out_m1) {
    const int c = blockIdx.x;
    const int b = blockIdx.y;
    const int tid = threadIdx.x;
    const int lane = tid & 63;
    const int w = tid >> 6;
    const int g = lane >> 3;    // k-slot (group) within wave: 0..7
    const int l8 = lane & 7;    // lane within group; owns floats l8*4 + j*32
    const float INV_TAU = 1.0f / 0.07f;
    const float INV3 = 1.0f / 3.0f;

    float4 q0[4], q1[4];
    #pragma unroll
    for (int j = 0; j < 4; ++j) {
        q0[j] = *(const float4*)(emb0 + b * D + j * 32 + l8 * 4);
        q1[j] = *(const float4*)(emb1 + b * D + j * 32 + l8 * 4);
    }

    float s1ij = 0.f, s1ji = 0.f, s1i0 = 0.f, s1i1 = 0.f;
    float s3ij = 0.f, s3ji = 0.f, s3i0 = 0.f, s3i1 = 0.f;
    float wa = 0.f, wb = 0.f, wc = 0.f, wd = 0.f;

    __shared__ float red[4][12];
    __shared__ float sps[6];  // only wave 0 touches sps (init, k==0/1, read): no race

    const int k0 = c * CS;
    const int kend = (k0 + CS < KTOT) ? k0 + CS : KTOT;
    const int kbase = k0 + w * 8 + g;
    const int posbase = b * 2;
    const int negbase = b * NEGK - 2;

    // copy-slice addressing: linear block id * 256 + tid, stepped 7x
    const int cbase = (b * CHUNKS + c) * 256 + tid;
    const nt4* cm0 = (const nt4*)mem0;
    const nt4* cm1 = (const nt4*)mem1;
    nt4* co0 = (nt4*)out_m0;
    nt4* co1 = (nt4*)out_m1;

    if (tid < 6) sps[tid] = 0.f;

    float4 A0[4], A1[4], B0[4], B1[4];

#define FETCH(IT, R0, R1) do {                                               \
    const int kf = kbase + (IT) * 32;                                        \
    const int kc = (kf < kend) ? kf : (kend - 1);                            \
    const int r = (kc < 2) ? pos_idx[posbase + kc] : neg_idx[negbase + kc];  \
    const float* p0 = mem0 + r * D + l8 * 4;                                 \
    const float* p1 = mem1 + r * D + l8 * 4;                                 \
    _Pragma("unroll")                                                        \
    for (int j = 0; j < 4; ++j) {                                            \
        R0[j] = *(const float4*)(p0 + j * 32);                               \
        R1[j] = *(const float4*)(p1 + j * 32);                               \
    }                                                                        \
} while (0)

#define COMPUTE(IT, R0, R1) do {                                             \
    const int kk = kbase + (IT) * 32;                                        \
    float pij = 0.f, pii = 0.f, pji = 0.f, pjj = 0.f;                        \
    _Pragma("unroll")                                                        \
    for (int j = 0; j < 4; ++j) {                                            \
        pij += R0[j].x * q1[j].x + R0[j].y * q1[j].y                         \
             + R0[j].z * q1[j].z + R0[j].w * q1[j].w;                        \
        pii += R0[j].x * q0[j].x + R0[j].y * q0[j].y                         \
             + R0[j].z * q0[j].z + R0[j].w * q0[j].w;                        \
        pji += R1[j].x * q0[j].x + R1[j].y * q0[j].y                         \
             + R1[j].z * q0[j].z + R1[j].w * q0[j].w;                        \
        pjj += R1[j].x * q1[j].x + R1[j].y * q1[j].y                         \
             + R1[j].z * q1[j].z + R1[j].w * q1[j].w;                        \
    }                                                                        \
    _Pragma("unroll")                                                        \
    for (int off = 1; off < 8; off <<= 1) {                                  \
        pij += __shfl_xor(pij, off, 64);                                     \
        pii += __shfl_xor(pii, off, 64);                                     \
        pji += __shfl_xor(pji, off, 64);                                     \
        pjj += __shfl_xor(pjj, off, 64);                                     \
    }                                                                        \
    const float mA = (kk < kend) ? 1.f : 0.f;                                \
    const float mI = (kk >= 1) ? mA : 0.f;                                   \
    const float cij = pij * INV_TAU, ci0 = pii * INV_TAU;                    \
    const float cji = pji * INV_TAU, ci1 = pjj * INV_TAU;                    \
    const float e3ij = __expf(cij * INV3), e3ji = __expf(cji * INV3);        \
    const float e3i0 = __expf(ci0 * INV3), e3i1 = __expf(ci1 * INV3);        \
    s1ij += mA * __expf(cij);                                                \
    s1ji += mA * __expf(cji);                                                \
    s3ij += mA * e3ij;                                                       \
    s3ji += mA * e3ji;                                                       \
    wa += mA * e3ji * (cji - cij);                                           \
    wb += mA * e3ij * (cij - cji);                                           \
    s1i0 += mI * __expf(ci0);                                                \
    s1i1 += mI * __expf(ci1);                                                \
    s3i0 += mI * e3i0;                                                       \
    s3i1 += mI * e3i1;                                                       \
    wc += mI * e3i1 * (ci1 - ci0);                                           \
    wd += mI * e3i0 * (ci0 - ci1);                                           \
    if (kk == 0 && l8 == 0) { sps[0] = cij; sps[2] = cji; }                  \
    if (kk == 1 && l8 == 0) { sps[1] = cij; sps[3] = cji;                    \
                              sps[4] = ci0; sps[5] = ci1; }                  \
} while (0)

// one copy step: CACHED loads (LLC-resident), NT stores (no write-allocate)
#define COPYSTEP(S) do {                                                     \
    const int ci = (S) * NTHREADS_TOTAL + cbase;                             \
    if (ci < N4) {                                                           \
        nt4 ca = cm0[ci];                                                    \
        nt4 cb = cm1[ci];                                                    \
        __builtin_nontemporal_store(ca, co0 + ci);                           \
        __builtin_nontemporal_store(cb, co1 + ci);                           \
    }                                                                        \
} while (0)

    // 17 iterations total (17*32 >= CS), uniform trip count; tails masked by mA.
    // 7 copy steps (7 * 524288 >= 3.2M) interleaved into the 8 loop bodies.
    FETCH(0, A0, A1);
    for (int it = 0; it < 16; it += 2) {
        FETCH(it + 1, B0, B1);
        const int s = it >> 1;
        if (s < 7) COPYSTEP(s);
        COMPUTE(it, A0, A1);
        FETCH(it + 2, A0, A1);
        COMPUTE(it + 1, B0, B1);
    }
    COMPUTE(16, A0, A1);

#undef FETCH
#undef COMPUTE
#undef COPYSTEP

    // lanes within a group hold identical reduced values; xor over 8/16/32
    // picks one lane per group -> wave-wide sums in every lane.
    float v[12] = {s1ij, s1ji, s1i0, s1i1, s3ij, s3ji, s3i0, s3i1, wa, wb, wc, wd};
    #pragma unroll
    for (int j = 0; j < 12; ++j) {
        v[j] += __shfl_xor(v[j], 8, 64);
        v[j] += __shfl_xor(v[j], 16, 64);
        v[j] += __shfl_xor(v[j], 32, 64);
    }
    if (lane == 0) {
        #pragma unroll
        for (int j = 0; j < 12; ++j) red[w][j] = v[j];
    }
    __syncthreads();
    float* outp = partials + (b * CHUNKS + c) * 20;
    if (tid < 12) outp[tid] = red[0][tid] + red[1][tid] + red[2][tid] + red[3][tid];
    else if (tid < 18) outp[tid] = sps[tid - 12];
}

// Merged finalize + update_rows: 129 blocks x 128 threads.
// Blocks [0,128): momentum row update for b = blockIdx.x.
// Block 128: merge chunk partials -> 4 scalars.
__global__ void final_update(const float* __restrict__ partials, float* __restrict__ out,
                             const float* __restrict__ emb0, const float* __restrict__ emb1,
                             const float* __restrict__ mem0, const float* __restrict__ mem1,
                             const int* __restrict__ pos_idx,
                             float* __restrict__ o0, float* __restrict__ o1) {
    if (blockIdx.x < B) {
        // ---- update_rows body ----
        const int b = blockIdx.x;
        const int tid = threadIdx.x;  // 128
        const int lane = tid & 63;
        const int net = tid >> 6;
        const int p0 = pos_idx[b * 2];
        bool skip = false;
        for (int b2 = b + 1; b2 < B; ++b2)
            if (pos_idx[b2 * 2] == p0) skip = true;  // numpy scatter: last write wins
        if (skip) return;  // uniform across block
        const float* mem = net ? mem1 : mem0;
        const float* emb = net ? emb1 : emb0;
        float* o = net ? o1 : o0;
        const float2 mv = *(const float2*)(mem + p0 * D + 2 * lane);
        const float2 ev = *(const float2*)(emb + b * D + 2 * lane);
        const float ux = 0.5f * mv.x + 0.5f * ev.x;
        const float uy = 0.5f * mv.y + 0.5f * ev.y;
        float ss = ux * ux + uy * uy;
        #pragma unroll
        for (int off = 1; off < 64; off <<= 1) ss += __shfl_xor(ss, off, 64);
        const float inv = 1.0f / sqrtf(ss);
        float2 wv; wv.x = ux * inv; wv.y = uy * inv;
        *(float2*)(o + p0 * D + 2 * lane) = wv;
        return;
    }
    // ---- finalize body ----
    const int b = threadIdx.x;
    float a[12];
    #pragma unroll
    for (int j = 0; j < 12; ++j) a[j] = 0.f;
    for (int c = 0; c < CHUNKS; ++c) {
        const float* p = partials + (b * CHUNKS + c) * 20;
        #pragma unroll
        for (int j = 0; j < 12; ++j) a[j] += p[j];
    }
    const float* e = partials + (b * CHUNKS) * 20 + 12;
    const float cij0 = e[0], cij1 = e[1], cji0 = e[2], cji1 = e[3], i01 = e[4], i11 = e[5];
    // a: 0 s1ij, 1 s1ji, 2 s1i0, 3 s1i1, 4 s3ij, 5 s3ji, 6 s3i0, 7 s3i1, 8 wa, 9 wb, 10 wc, 11 wd
    const float icl_b = -((cij0 + cij1) * 0.5f - __logf(a[0]))
                        - ((cji0 + cji1) * 0.5f - __logf(a[1]));
    const float vcl_b = -(i01 - __logf(a[2])) - (i11 - __logf(a[3]));
    // kld(X,Y)+kld(Y,X): lse terms cancel; = 3/B * (wa/s3_Y + wb/s3_X), B-mean later
    const float sicl_b = 3.0f * (a[8] / a[5] + a[9] / a[4]);
    const float svcl_b = 3.0f * (a[10] / a[7] + a[11] / a[6]);
    __shared__ float r[4][128];
    r[0][b] = vcl_b; r[1][b] = svcl_b; r[2][b] = icl_b; r[3][b] = sicl_b;
    __syncthreads();
    for (int s = 64; s > 0; s >>= 1) {
        if (b < s) {
            r[0][b] += r[0][b + s]; r[1][b] += r[1][b + s];
            r[2][b] += r[2][b + s]; r[3][b] += r[3][b + s];
        }
        __syncthreads();
    }
    if (b == 0) {
        out[0] = r[0][0] * (1.0f / 128.f);
        out[1] = r[1][0] * (1.0f / 128.f);
        out[2] = r[2][0] * (1.0f / 128.f);
        out[3] = r[3][0] * (1.0f / 128.f);
    }
}

extern "C" void kernel_launch(void* const* d_in, const int* in_sizes, int n_in,
                              void* d_out, int out_size, void* d_ws, size_t ws_size,
                              hipStream_t stream) {
    const float* emb0 = (const float*)d_in[0];
    const float* emb1 = (const float*)d_in[1];
    const float* mem0 = (const float*)d_in[2];
    const float* mem1 = (const float*)d_in[3];
    const int* pos_idx = (const int*)d_in[4];
    const int* neg_idx = (const int*)d_in[5];
    float* out = (float*)d_out;
    float* partials = (float*)d_ws;  // needs 128*16*20*4 = 160 KiB

    float* out_m0 = out + 4;
    float* out_m1 = out + 4 + NMEM * D;

    gather_copy<<<dim3(CHUNKS, B), 256, 0, stream>>>(emb0, emb1, mem0, mem1,
                                                     pos_idx, neg_idx, partials,
                                                     out_m0, out_m1);
    final_update<<<B + 1, 128, 0, stream>>>(partials, out, emb0, emb1,
                                            mem0, mem1, pos_idx, out_m0, out_m1);
}

// Round 7
// 331.719 us; speedup vs baseline: 1.5009x; 1.5009x over previous
//
#include <hip/hip_runtime.h>
#include <math.h>

#define B 128
#define D 128
#define NMEM 100000
#define KTOT 8194
#define NEGK 8192
#define CHUNKS 16
#define CS 513  // ceil(8194/16)
#define N4 (NMEM * D / 4)  // 3,200,000 float4 per mem array

// plain vector type for nontemporal builtins (HIP_vector_type is rejected)
typedef float nt4 __attribute__((ext_vector_type(4)));

// gather_logits: EXACT round-1 structure (best measured: 161 us, VGPR 64,
// FETCH 510 MB). 8 lanes per k (3-step xor reduce), 8 k's per wave-iteration,
// register double-buffered row gather. (256,4): VGPR cap 64 (= compiler's
// natural allocation; (256,8) caps at 32 -> scratch spills, round 4).
// Do not fuse streaming traffic in here: it flushes L2 and collapses the
// gather's ~50% hit rate (rounds 3/6: FETCH 510 MB -> 1.08 GB).
__global__ __launch_bounds__(256, 4) void gather_logits(
        const float* __restrict__ emb0, const float* __restrict__ emb1,
        const float* __restrict__ mem0, const float* __restrict__ mem1,
        const int* __restrict__ pos_idx, const int* __restrict__ neg_idx,
        float* __restrict__ partials) {
    const int c = blockIdx.x;
    const int b = blockIdx.y;
    const int tid = threadIdx.x;
    const int lane = tid & 63;
    const int w = tid >> 6;
    const int g = lane >> 3;    // k-slot (group) within wave: 0..7
    const int l8 = lane & 7;    // lane within group; owns floats l8*4 + j*32
    const float INV_TAU = 1.0f / 0.07f;
    const float INV3 = 1.0f / 3.0f;

    float4 q0[4], q1[4];
    #pragma unroll
    for (int j = 0; j < 4; ++j) {
        q0[j] = *(const float4*)(emb0 + b * D + j * 32 + l8 * 4);
        q1[j] = *(const float4*)(emb1 + b * D + j * 32 + l8 * 4);
    }

    float s1ij = 0.f, s1ji = 0.f, s1i0 = 0.f, s1i1 = 0.f;
    float s3ij = 0.f, s3ji = 0.f, s3i0 = 0.f, s3i1 = 0.f;
    float wa = 0.f, wb = 0.f, wc = 0.f, wd = 0.f;

    __shared__ float red[4][12];
    __shared__ float sps[6];  // only wave 0 touches sps (init, k==0/1, read): no race

    const int k0 = c * CS;
    const int kend = (k0 + CS < KTOT) ? k0 + CS : KTOT;
    const int kbase = k0 + w * 8 + g;
    const int posbase = b * 2;
    const int negbase = b * NEGK - 2;

    if (tid < 6) sps[tid] = 0.f;

    float4 A0[4], A1[4], B0[4], B1[4];

#define FETCH(IT, R0, R1) do {                                               \
    const int kf = kbase + (IT) * 32;                                        \
    const int kc = (kf < kend) ? kf : (kend - 1);                            \
    const int r = (kc < 2) ? pos_idx[posbase + kc] : neg_idx[negbase + kc];  \
    const float* p0 = mem0 + r * D + l8 * 4;                                 \
    const float* p1 = mem1 + r * D + l8 * 4;                                 \
    _Pragma("unroll")                                                        \
    for (int j = 0; j < 4; ++j) {                                            \
        R0[j] = *(const float4*)(p0 + j * 32);                               \
        R1[j] = *(const float4*)(p1 + j * 32);                               \
    }                                                                        \
} while (0)

#define COMPUTE(IT, R0, R1) do {                                             \
    const int kk = kbase + (IT) * 32;                                        \
    float pij = 0.f, pii = 0.f, pji = 0.f, pjj = 0.f;                        \
    _Pragma("unroll")                                                        \
    for (int j = 0; j < 4; ++j) {                                            \
        pij += R0[j].x * q1[j].x + R0[j].y * q1[j].y                         \
             + R0[j].z * q1[j].z + R0[j].w * q1[j].w;                        \
        pii += R0[j].x * q0[j].x + R0[j].y * q0[j].y                         \
             + R0[j].z * q0[j].z + R0[j].w * q0[j].w;                        \
        pji += R1[j].x * q0[j].x + R1[j].y * q0[j].y                         \
             + R1[j].z * q0[j].z + R1[j].w * q0[j].w;                        \
        pjj += R1[j].x * q1[j].x + R1[j].y * q1[j].y                         \
             + R1[j].z * q1[j].z + R1[j].w * q1[j].w;                        \
    }                                                                        \
    _Pragma("unroll")                                                        \
    for (int off = 1; off < 8; off <<= 1) {                                  \
        pij += __shfl_xor(pij, off, 64);                                     \
        pii += __shfl_xor(pii, off, 64);                                     \
        pji += __shfl_xor(pji, off, 64);                                     \
        pjj += __shfl_xor(pjj, off, 64);                                     \
    }                                                                        \
    const float mA = (kk < kend) ? 1.f : 0.f;                                \
    const float mI = (kk >= 1) ? mA : 0.f;                                   \
    const float cij = pij * INV_TAU, ci0 = pii * INV_TAU;                    \
    const float cji = pji * INV_TAU, ci1 = pjj * INV_TAU;                    \
    const float e3ij = __expf(cij * INV3), e3ji = __expf(cji * INV3);        \
    const float e3i0 = __expf(ci0 * INV3), e3i1 = __expf(ci1 * INV3);        \
    s1ij += mA * __expf(cij);                                                \
    s1ji += mA * __expf(cji);                                                \
    s3ij += mA * e3ij;                                                       \
    s3ji += mA * e3ji;                                                       \
    wa += mA * e3ji * (cji - cij);                                           \
    wb += mA * e3ij * (cij - cji);                                           \
    s1i0 += mI * __expf(ci0);                                                \
    s1i1 += mI * __expf(ci1);                                                \
    s3i0 += mI * e3i0;                                                       \
    s3i1 += mI * e3i1;                                                       \
    wc += mI * e3i1 * (ci1 - ci0);                                           \
    wd += mI * e3i0 * (ci0 - ci1);                                           \
    if (kk == 0 && l8 == 0) { sps[0] = cij; sps[2] = cji; }                  \
    if (kk == 1 && l8 == 0) { sps[1] = cij; sps[3] = cji;                    \
                              sps[4] = ci0; sps[5] = ci1; }                  \
} while (0)

    // 17 iterations total (17*32 >= CS), uniform trip count; tails masked by mA.
    FETCH(0, A0, A1);
    for (int it = 0; it < 16; it += 2) {
        FETCH(it + 1, B0, B1);
        COMPUTE(it, A0, A1);
        FETCH(it + 2, A0, A1);
        COMPUTE(it + 1, B0, B1);
    }
    COMPUTE(16, A0, A1);

#undef FETCH
#undef COMPUTE

    // lanes within a group hold identical reduced values; xor over 8/16/32
    // picks one lane per group -> wave-wide sums in every lane.
    float v[12] = {s1ij, s1ji, s1i0, s1i1, s3ij, s3ji, s3i0, s3i1, wa, wb, wc, wd};
    #pragma unroll
    for (int j = 0; j < 12; ++j) {
        v[j] += __shfl_xor(v[j], 8, 64);
        v[j] += __shfl_xor(v[j], 16, 64);
        v[j] += __shfl_xor(v[j], 32, 64);
    }
    if (lane == 0) {
        #pragma unroll
        for (int j = 0; j < 12; ++j) red[w][j] = v[j];
    }
    __syncthreads();
    float* outp = partials + (b * CHUNKS + c) * 20;
    if (tid < 12) outp[tid] = red[0][tid] + red[1][tid] + red[2][tid] + red[3][tid];
    else if (tid < 18) outp[tid] = sps[tid - 12];
}

// mem copy: cached loads, non-temporal stores (write-once 102 MB stream,
// skip write-allocate so the stores don't churn L2).
__global__ void copy_mems(const nt4* __restrict__ m0, const nt4* __restrict__ m1,
                          nt4* __restrict__ o0, nt4* __restrict__ o1) {
    for (int i = blockIdx.x * blockDim.x + threadIdx.x; i < N4; i += gridDim.x * blockDim.x) {
        nt4 a = m0[i];
        nt4 b = m1[i];
        __builtin_nontemporal_store(a, o0 + i);
        __builtin_nontemporal_store(b, o1 + i);
    }
}

// Merged finalize + update_rows: 129 blocks x 128 threads.
// Blocks [0,128): momentum row update for b = blockIdx.x (after copy!).
// Block 128: merge chunk partials -> 4 scalars.
__global__ void final_update(const float* __restrict__ partials, float* __restrict__ out,
                             const float* __restrict__ emb0, const float* __restrict__ emb1,
                             const float* __restrict__ mem0, const float* __restrict__ mem1,
                             const int* __restrict__ pos_idx,
                             float* __restrict__ o0, float* __restrict__ o1) {
    if (blockIdx.x < B) {
        // ---- update_rows body ----
        const int b = blockIdx.x;
        const int tid = threadIdx.x;  // 128
        const int lane = tid & 63;
        const int net = tid >> 6;
        const int p0 = pos_idx[b * 2];
        bool skip = false;
        for (int b2 = b + 1; b2 < B; ++b2)
            if (pos_idx[b2 * 2] == p0) skip = true;  // numpy scatter: last write wins
        if (skip) return;  // uniform across block
        const float* mem = net ? mem1 : mem0;
        const float* emb = net ? emb1 : emb0;
        float* o = net ? o1 : o0;
        const float2 mv = *(const float2*)(mem + p0 * D + 2 * lane);
        const float2 ev = *(const float2*)(emb + b * D + 2 * lane);
        const float ux = 0.5f * mv.x + 0.5f * ev.x;
        const float uy = 0.5f * mv.y + 0.5f * ev.y;
        float ss = ux * ux + uy * uy;
        #pragma unroll
        for (int off = 1; off < 64; off <<= 1) ss += __shfl_xor(ss, off, 64);
        const float inv = 1.0f / sqrtf(ss);
        float2 wv; wv.x = ux * inv; wv.y = uy * inv;
        *(float2*)(o + p0 * D + 2 * lane) = wv;
        return;
    }
    // ---- finalize body ----
    const int b = threadIdx.x;
    float a[12];
    #pragma unroll
    for (int j = 0; j < 12; ++j) a[j] = 0.f;
    for (int c = 0; c < CHUNKS; ++c) {
        const float* p = partials + (b * CHUNKS + c) * 20;
        #pragma unroll
        for (int j = 0; j < 12; ++j) a[j] += p[j];
    }
    const float* e = partials + (b * CHUNKS) * 20 + 12;
    const float cij0 = e[0], cij1 = e[1], cji0 = e[2], cji1 = e[3], i01 = e[4], i11 = e[5];
    // a: 0 s1ij, 1 s1ji, 2 s1i0, 3 s1i1, 4 s3ij, 5 s3ji, 6 s3i0, 7 s3i1, 8 wa, 9 wb, 10 wc, 11 wd
    const float icl_b = -((cij0 + cij1) * 0.5f - __logf(a[0]))
                        - ((cji0 + cji1) * 0.5f - __logf(a[1]));
    const float vcl_b = -(i01 - __logf(a[2])) - (i11 - __logf(a[3]));
    // kld(X,Y)+kld(Y,X): lse terms cancel; = 3/B * (wa/s3_Y + wb/s3_X), B-mean later
    const float sicl_b = 3.0f * (a[8] / a[5] + a[9] / a[4]);
    const float svcl_b = 3.0f * (a[10] / a[7] + a[11] / a[6]);
    __shared__ float r[4][128];
    r[0][b] = vcl_b; r[1][b] = svcl_b; r[2][b] = icl_b; r[3][b] = sicl_b;
    __syncthreads();
    for (int s = 64; s > 0; s >>= 1) {
        if (b < s) {
            r[0][b] += r[0][b + s]; r[1][b] += r[1][b + s];
            r[2][b] += r[2][b + s]; r[3][b] += r[3][b + s];
        }
        __syncthreads();
    }
    if (b == 0) {
        out[0] = r[0][0] * (1.0f / 128.f);
        out[1] = r[1][0] * (1.0f / 128.f);
        out[2] = r[2][0] * (1.0f / 128.f);
        out[3] = r[3][0] * (1.0f / 128.f);
    }
}

extern "C" void kernel_launch(void* const* d_in, const int* in_sizes, int n_in,
                              void* d_out, int out_size, void* d_ws, size_t ws_size,
                              hipStream_t stream) {
    const float* emb0 = (const float*)d_in[0];
    const float* emb1 = (const float*)d_in[1];
    const float* mem0 = (const float*)d_in[2];
    const float* mem1 = (const float*)d_in[3];
    const int* pos_idx = (const int*)d_in[4];
    const int* neg_idx = (const int*)d_in[5];
    float* out = (float*)d_out;
    float* partials = (float*)d_ws;  // needs 128*16*20*4 = 160 KiB

    float* out_m0 = out + 4;
    float* out_m1 = out + 4 + NMEM * D;

    gather_logits<<<dim3(CHUNKS, B), 256, 0, stream>>>(emb0, emb1, mem0, mem1,
                                                       pos_idx, neg_idx, partials);
    copy_mems<<<4096, 256, 0, stream>>>((const nt4*)mem0, (const nt4*)mem1,
                                        (nt4*)out_m0, (nt4*)out_m1);
    final_update<<<B + 1, 128, 0, stream>>>(partials, out, emb0, emb1,
                                            mem0, mem1, pos_idx, out_m0, out_m1);
}